// Round 1
// baseline (1016.005 us; speedup 1.0000x reference)
//
#include <hip/hip_runtime.h>
#include <hip/hip_bf16.h>

#define HDIM 128

// ---------------------------------------------------------------------------
// GEMM: out[r][c] = sum_k A[r][k] * W[k][c] (+ bias[c] if bias != nullptr)
// ---------------------------------------------------------------------------
__global__ __launch_bounds__(256) void gemm128(const float* __restrict__ A,
                                               const float* __restrict__ W,
                                               const float* __restrict__ bias,
                                               float* __restrict__ out, int n) {
    int t = blockIdx.x * 256 + threadIdx.x;
    int row = t >> 5;
    int c4 = (t & 31) << 2;
    if (row >= n) return;
    const float* a = A + (size_t)row * HDIM;
    float4 acc;
    if (bias) {
        acc = *(const float4*)(bias + c4);
    } else {
        acc = make_float4(0.f, 0.f, 0.f, 0.f);
    }
#pragma unroll 16
    for (int k = 0; k < HDIM; ++k) {
        float av = a[k];
        float4 wv = *(const float4*)(W + (size_t)k * HDIM + c4);
        acc.x += av * wv.x;
        acc.y += av * wv.y;
        acc.z += av * wv.z;
        acc.w += av * wv.w;
    }
    *(float4*)(out + (size_t)row * HDIM + c4) = acc;
}

// init: C[i][f] = bias[f]
__global__ __launch_bounds__(256) void init_bias(float* __restrict__ C,
                                                 const float* __restrict__ b,
                                                 int total) {
    int i = blockIdx.x * 256 + threadIdx.x;
    if (i < total) C[i] = b[i & (HDIM - 1)];
}

// scatter: AGG[dst] += M[src] for real edges and self loops
__global__ __launch_bounds__(256) void scatter_add(const float* __restrict__ M,
                                                   const int* __restrict__ ei,
                                                   int E, int n,
                                                   float* __restrict__ AGG) {
    long long t = (long long)blockIdx.x * 256 + threadIdx.x;
    int e = (int)(t >> 7);
    int f = (int)(t & (HDIM - 1));
    int nTot = E + n;
    if (e >= nTot) return;
    int s, d;
    if (e < E) {
        s = ei[e];
        d = ei[E + e];
    } else {
        s = d = e - E;
    }
    if ((unsigned)s < (unsigned)n && (unsigned)d < (unsigned)n) {
        float v = M[(size_t)s * HDIM + f];
        __hip_atomic_fetch_add(AGG + (size_t)d * HDIM + f, v,
                               __ATOMIC_RELAXED, __HIP_MEMORY_SCOPE_AGENT);
    }
}

// elementwise tanh
__global__ __launch_bounds__(256) void tanh_ew(const float* __restrict__ in,
                                               float* __restrict__ out,
                                               int total) {
    int i = blockIdx.x * 256 + threadIdx.x;
    if (i < total) out[i] = tanhf(in[i]);
}

// head: per node (AGG2 already includes b2 via init_bias):
// h2 = tanh(AGG2 row); hp = tanh(h2@cp_w+cp_b); out = hp@cls_w+cls_b
__global__ __launch_bounds__(256) void head(const float* __restrict__ AGG2,
                                            const float* __restrict__ cp_w,
                                            const float* __restrict__ cp_b,
                                            const float* __restrict__ cls_w,
                                            const float* __restrict__ cls_b,
                                            float* __restrict__ out, int n) {
    int node = (blockIdx.x * 256 + threadIdx.x) >> 6;
    int lane = threadIdx.x & 63;
    if (node >= n) return;
    float2 av = *(const float2*)(AGG2 + (size_t)node * HDIM + lane * 2);
    float h0 = tanhf(av.x);
    float h1 = tanhf(av.y);
    float4 w = *(const float4*)(cp_w + lane * 4);
    float s0 = h0 * w.x + h1 * w.z;
    float s1 = h0 * w.y + h1 * w.w;
#pragma unroll
    for (int off = 32; off; off >>= 1) {
        s0 += __shfl_xor(s0, off);
        s1 += __shfl_xor(s1, off);
    }
    if (lane == 0) {
        float p0 = tanhf(s0 + cp_b[0]);
        float p1 = tanhf(s1 + cp_b[1]);
        float4 o;
        o.x = p0 * cls_w[0] + p1 * cls_w[4] + cls_b[0];
        o.y = p0 * cls_w[1] + p1 * cls_w[5] + cls_b[1];
        o.z = p0 * cls_w[2] + p1 * cls_w[6] + cls_b[2];
        o.w = p0 * cls_w[3] + p1 * cls_w[7] + cls_b[3];
        *(float4*)(out + (size_t)node * 4) = o;
        float* hout = out + (size_t)n * 4;
        *(float2*)(hout + (size_t)node * 2) = make_float2(p0, p1);
    }
}

extern "C" void kernel_launch(void* const* d_in, const int* in_sizes, int n_in,
                              void* d_out, int out_size, void* d_ws, size_t ws_size,
                              hipStream_t stream) {
    const float* x     = (const float*)d_in[0];
    const int*   ei    = (const int*)d_in[1];
    const float* fw    = (const float*)d_in[2];
    const float* fb    = (const float*)d_in[3];
    const float* w1    = (const float*)d_in[4];
    const float* b1    = (const float*)d_in[5];
    const float* w2    = (const float*)d_in[6];
    const float* b2    = (const float*)d_in[7];
    const float* cp_w  = (const float*)d_in[8];
    const float* cp_b  = (const float*)d_in[9];
    const float* cls_w = (const float*)d_in[10];
    const float* cls_b = (const float*)d_in[11];
    float* out = (float*)d_out;

    int n = in_sizes[0] / HDIM;
    int E = in_sizes[1] / 2;
    size_t nh = (size_t)n * HDIM;

    float* A = (float*)d_ws;  // H0 -> h1
    float* B = A + nh;        // messages
    float* C = B + nh;        // accumulator

    int gemmBlocks = (n * 32 + 255) / 256;
    int ewBlocks   = (int)((nh + 255) / 256);
    long long scatterThreads = (long long)(E + n) * HDIM;
    int scatterBlocks = (int)((scatterThreads + 255) / 256);
    int headBlocks = (n + 3) / 4;

    gemm128<<<gemmBlocks, 256, 0, stream>>>(x, fw, fb, A, n);

    gemm128<<<gemmBlocks, 256, 0, stream>>>(A, w1, nullptr, B, n);
    init_bias<<<ewBlocks, 256, 0, stream>>>(C, b1, (int)nh);
    scatter_add<<<scatterBlocks, 256, 0, stream>>>(B, ei, E, n, C);
    tanh_ew<<<ewBlocks, 256, 0, stream>>>(C, A, (int)nh);

    gemm128<<<gemmBlocks, 256, 0, stream>>>(A, w2, nullptr, B, n);
    init_bias<<<ewBlocks, 256, 0, stream>>>(C, b2, (int)nh);
    scatter_add<<<scatterBlocks, 256, 0, stream>>>(B, ei, E, n, C);

    head<<<headBlocks, 256, 0, stream>>>(C, cp_w, cp_b, cls_w, cls_b, out, n);
}

// Round 2
// 444.743 us; speedup vs baseline: 2.2845x; 2.2845x over previous
//
#include <hip/hip_runtime.h>

#define HDIM 128
#define BM 64
#define KB 16

// ---------------------------------------------------------------------------
// Tiled fp32 GEMM: out[n,128] = A[n,128] @ W[128,128] (+bias).
// Block: 256 threads, 64-row output tile, full 128 cols.
// Per thread: 4x8 register micro-tile. K staged in LDS in KB=16 slices.
// ---------------------------------------------------------------------------
__global__ __launch_bounds__(256) void gemm_tiled(
    const float* __restrict__ A, const float* __restrict__ W,
    const float* __restrict__ bias, float* __restrict__ out, int n) {
  __shared__ float sA[KB][BM];    // transposed: sA[k][row]
  __shared__ float sW[KB][HDIM];
  const int tid = threadIdx.x;
  const int tx = tid & 15;        // col group: cols tx*8 .. tx*8+7
  const int ty = tid >> 4;        // row group: rows ty*4 .. ty*4+3
  const int block_row = blockIdx.x * BM;

  float acc[4][8];
#pragma unroll
  for (int i = 0; i < 4; ++i)
#pragma unroll
    for (int j = 0; j < 8; ++j) acc[i][j] = 0.f;

  const int ar = tid >> 2;        // 0..63: row this thread stages
  const int ak = (tid & 3) << 2;  // 0,4,8,12: k-offset staged
  const int wk = tid >> 4;        // 0..15: W k-row staged
  const int wc = (tid & 15) << 3; // col offset staged

  for (int k0 = 0; k0 < HDIM; k0 += KB) {
    float4 av = make_float4(0.f, 0.f, 0.f, 0.f);
    int grow = block_row + ar;
    if (grow < n) av = *(const float4*)(A + (size_t)grow * HDIM + k0 + ak);
    sA[ak + 0][ar] = av.x; sA[ak + 1][ar] = av.y;
    sA[ak + 2][ar] = av.z; sA[ak + 3][ar] = av.w;

    float4 w0 = *(const float4*)(W + (size_t)(k0 + wk) * HDIM + wc);
    float4 w1 = *(const float4*)(W + (size_t)(k0 + wk) * HDIM + wc + 4);
    *(float4*)&sW[wk][wc] = w0;
    *(float4*)&sW[wk][wc + 4] = w1;
    __syncthreads();

#pragma unroll
    for (int k = 0; k < KB; ++k) {
      float4 a = *(const float4*)&sA[k][ty * 4];
      float4 wA = *(const float4*)&sW[k][tx * 8];
      float4 wB = *(const float4*)&sW[k][tx * 8 + 4];
      float av4[4] = {a.x, a.y, a.z, a.w};
      float wv[8] = {wA.x, wA.y, wA.z, wA.w, wB.x, wB.y, wB.z, wB.w};
#pragma unroll
      for (int i = 0; i < 4; ++i)
#pragma unroll
        for (int j = 0; j < 8; ++j) acc[i][j] += av4[i] * wv[j];
    }
    __syncthreads();
  }

  float bj[8];
#pragma unroll
  for (int j = 0; j < 8; ++j) bj[j] = bias ? bias[tx * 8 + j] : 0.f;
#pragma unroll
  for (int i = 0; i < 4; ++i) {
    int grow = block_row + ty * 4 + i;
    if (grow < n) {
      float o[8];
#pragma unroll
      for (int j = 0; j < 8; ++j) o[j] = acc[i][j] + bj[j];
      *(float4*)(out + (size_t)grow * HDIM + tx * 8) = *(float4*)&o[0];
      *(float4*)(out + (size_t)grow * HDIM + tx * 8 + 4) = *(float4*)&o[4];
    }
  }
}

// ---------------------------------------------------------------------------
// CSR build: histogram of dst, single-block exclusive scan, slot fill.
// ---------------------------------------------------------------------------
__global__ __launch_bounds__(256) void hist_dst(const int* __restrict__ ei,
                                                int E, int n,
                                                int* __restrict__ deg) {
  int e = blockIdx.x * 256 + threadIdx.x;
  if (e < E) {
    int d = ei[E + e];
    if ((unsigned)d < (unsigned)n) atomicAdd(&deg[d], 1);
  }
}

__global__ __launch_bounds__(1024) void scan_csr(const int* __restrict__ deg,
                                                 int* __restrict__ off,
                                                 int* __restrict__ cur, int n) {
  __shared__ int partial[1024];
  int tid = threadIdx.x;
  int per = (n + 1023) >> 10;
  int start = tid * per;
  int end = min(start + per, n);
  int sum = 0;
  for (int i = start; i < end; ++i) sum += deg[i];
  partial[tid] = sum;
  __syncthreads();
  for (int d = 1; d < 1024; d <<= 1) {
    int v = 0;
    if (tid >= d) v = partial[tid - d];
    __syncthreads();
    if (tid >= d) partial[tid] += v;
    __syncthreads();
  }
  int run = tid ? partial[tid - 1] : 0;
  for (int i = start; i < end; ++i) {
    off[i] = run;
    cur[i] = run;
    run += deg[i];
  }
  if (tid == 1023) off[n] = partial[1023];
}

__global__ __launch_bounds__(256) void fill_csr(const int* __restrict__ ei,
                                                int E, int n,
                                                int* __restrict__ cur,
                                                int* __restrict__ csr) {
  int e = blockIdx.x * 256 + threadIdx.x;
  if (e < E) {
    int s = ei[e];
    int d = ei[E + e];
    if ((unsigned)d < (unsigned)n && (unsigned)s < (unsigned)n) {
      int slot = atomicAdd(&cur[d], 1);
      csr[slot] = s;
    }
  }
}

// ---------------------------------------------------------------------------
// agg_tanh: out[v] = tanh( bias + M[v] (self loop) + sum_{s in N(v)} M[s] ).
// One wave per node; lane owns float2 at feature lane*2.
// Edge src ids fetched once per 64-chunk, broadcast via shfl.
// ---------------------------------------------------------------------------
__global__ __launch_bounds__(256) void agg_tanh(const float* __restrict__ M,
                                                const int* __restrict__ off,
                                                const int* __restrict__ csr,
                                                const float* __restrict__ bias,
                                                float* __restrict__ out, int n) {
  int node = (blockIdx.x * 256 + threadIdx.x) >> 6;
  int lane = threadIdx.x & 63;
  if (node >= n) return;
  int f = lane * 2;
  float2 acc = *(const float2*)(M + (size_t)node * HDIM + f);  // self loop
  acc.x += bias[f];
  acc.y += bias[f + 1];
  int s = off[node], e = off[node + 1];
  for (int base = s; base < e; base += 64) {
    int idx = base + lane;
    int msrc = (idx < e) ? csr[idx] : 0;
    int cnt = min(64, e - base);
    for (int j = 0; j < cnt; ++j) {
      int src = __shfl(msrc, j);
      float2 v = *(const float2*)(M + (size_t)src * HDIM + f);
      acc.x += v.x;
      acc.y += v.y;
    }
  }
  acc.x = tanhf(acc.x);
  acc.y = tanhf(acc.y);
  *(float2*)(out + (size_t)node * HDIM + f) = acc;
}

// ---------------------------------------------------------------------------
// agg2_head: layer-2 aggregation fused with the head.
// h2 = tanh(b2 + self + sum); hp = tanh(h2 @ cp_w + cp_b);
// out[node] = hp @ cls_w + cls_b. d_out = [n*4 logits][n*2 hp].
// ---------------------------------------------------------------------------
__global__ __launch_bounds__(256) void agg2_head(
    const float* __restrict__ M, const int* __restrict__ off,
    const int* __restrict__ csr, const float* __restrict__ b2,
    const float* __restrict__ cp_w, const float* __restrict__ cp_b,
    const float* __restrict__ cls_w, const float* __restrict__ cls_b,
    float* __restrict__ out, int n) {
  int node = (blockIdx.x * 256 + threadIdx.x) >> 6;
  int lane = threadIdx.x & 63;
  if (node >= n) return;
  int f = lane * 2;
  float2 acc = *(const float2*)(M + (size_t)node * HDIM + f);
  acc.x += b2[f];
  acc.y += b2[f + 1];
  int s = off[node], e = off[node + 1];
  for (int base = s; base < e; base += 64) {
    int idx = base + lane;
    int msrc = (idx < e) ? csr[idx] : 0;
    int cnt = min(64, e - base);
    for (int j = 0; j < cnt; ++j) {
      int src = __shfl(msrc, j);
      float2 v = *(const float2*)(M + (size_t)src * HDIM + f);
      acc.x += v.x;
      acc.y += v.y;
    }
  }
  float h0 = tanhf(acc.x);
  float h1 = tanhf(acc.y);
  float4 w = *(const float4*)(cp_w + lane * 4);  // rows f, f+1 of [128,2]
  float s0 = h0 * w.x + h1 * w.z;
  float s1 = h0 * w.y + h1 * w.w;
#pragma unroll
  for (int offs = 32; offs; offs >>= 1) {
    s0 += __shfl_xor(s0, offs);
    s1 += __shfl_xor(s1, offs);
  }
  if (lane == 0) {
    float p0 = tanhf(s0 + cp_b[0]);
    float p1 = tanhf(s1 + cp_b[1]);
    float4 o;
    o.x = p0 * cls_w[0] + p1 * cls_w[4] + cls_b[0];
    o.y = p0 * cls_w[1] + p1 * cls_w[5] + cls_b[1];
    o.z = p0 * cls_w[2] + p1 * cls_w[6] + cls_b[2];
    o.w = p0 * cls_w[3] + p1 * cls_w[7] + cls_b[3];
    *(float4*)(out + (size_t)node * 4) = o;
    float* hout = out + (size_t)n * 4;
    *(float2*)(hout + (size_t)node * 2) = make_float2(p0, p1);
  }
}

extern "C" void kernel_launch(void* const* d_in, const int* in_sizes, int n_in,
                              void* d_out, int out_size, void* d_ws, size_t ws_size,
                              hipStream_t stream) {
  const float* x     = (const float*)d_in[0];
  const int*   ei    = (const int*)d_in[1];
  const float* fw    = (const float*)d_in[2];
  const float* fb    = (const float*)d_in[3];
  const float* w1    = (const float*)d_in[4];
  const float* b1    = (const float*)d_in[5];
  const float* w2    = (const float*)d_in[6];
  const float* b2    = (const float*)d_in[7];
  const float* cp_w  = (const float*)d_in[8];
  const float* cp_b  = (const float*)d_in[9];
  const float* cls_w = (const float*)d_in[10];
  const float* cls_b = (const float*)d_in[11];
  float* out = (float*)d_out;

  int n = in_sizes[0] / HDIM;
  int E = in_sizes[1] / 2;
  size_t nh = (size_t)n * HDIM;

  float* A = (float*)d_ws;        // H0 -> h1
  float* B = A + nh;              // messages M
  int* deg = (int*)(B + nh);
  int* off = deg + n;             // n+1 entries
  int* cur = off + n + 1;
  int* csr = cur + n;             // E entries

  int gemmBlocks = (n + BM - 1) / BM;
  int edgeBlocks = (E + 255) / 256;
  int aggBlocks = (n + 3) / 4;

  // CSR build (used by both layers)
  hipMemsetAsync(deg, 0, (size_t)n * sizeof(int), stream);
  hist_dst<<<edgeBlocks, 256, 0, stream>>>(ei, E, n, deg);
  scan_csr<<<1, 1024, 0, stream>>>(deg, off, cur, n);
  fill_csr<<<edgeBlocks, 256, 0, stream>>>(ei, E, n, cur, csr);

  // layer 0: A = x @ fw + fb
  gemm_tiled<<<gemmBlocks, 256, 0, stream>>>(x, fw, fb, A, n);
  // layer 1: B = A @ w1 ; A = tanh(b1 + agg(B))
  gemm_tiled<<<gemmBlocks, 256, 0, stream>>>(A, w1, nullptr, B, n);
  agg_tanh<<<aggBlocks, 256, 0, stream>>>(B, off, csr, b1, A, n);
  // layer 2: B = A @ w2 ; fused agg + head
  gemm_tiled<<<gemmBlocks, 256, 0, stream>>>(A, w2, nullptr, B, n);
  agg2_head<<<aggBlocks, 256, 0, stream>>>(B, off, csr, b2, cp_w, cp_b,
                                           cls_w, cls_b, out, n);
}

// Round 4
// 348.761 us; speedup vs baseline: 2.9132x; 1.2752x over previous
//
#include <hip/hip_runtime.h>

#define HDIM 128
#define BM 64
#define KB 16

// ---------------------------------------------------------------------------
// Tiled fp32 GEMM: out[n,128] = A[n,128] @ W[128,128] (+bias).
// Block: 256 threads, 64-row output tile, full 128 cols.
// Per thread: 4x8 register micro-tile. K staged in LDS in KB=16 slices.
// ---------------------------------------------------------------------------
__global__ __launch_bounds__(256) void gemm_tiled(
    const float* __restrict__ A, const float* __restrict__ W,
    const float* __restrict__ bias, float* __restrict__ out, int n) {
  __shared__ float sA[KB][BM];    // transposed: sA[k][row]
  __shared__ float sW[KB][HDIM];
  const int tid = threadIdx.x;
  const int tx = tid & 15;        // col group: cols tx*8 .. tx*8+7
  const int ty = tid >> 4;        // row group: rows ty*4 .. ty*4+3
  const int block_row = blockIdx.x * BM;

  float acc[4][8];
#pragma unroll
  for (int i = 0; i < 4; ++i)
#pragma unroll
    for (int j = 0; j < 8; ++j) acc[i][j] = 0.f;

  const int ar = tid >> 2;        // 0..63: row this thread stages
  const int ak = (tid & 3) << 2;  // 0,4,8,12: k-offset staged
  const int wk = tid >> 4;        // 0..15: W k-row staged
  const int wc = (tid & 15) << 3; // col offset staged

  for (int k0 = 0; k0 < HDIM; k0 += KB) {
    float4 av = make_float4(0.f, 0.f, 0.f, 0.f);
    int grow = block_row + ar;
    if (grow < n) av = *(const float4*)(A + (size_t)grow * HDIM + k0 + ak);
    sA[ak + 0][ar] = av.x; sA[ak + 1][ar] = av.y;
    sA[ak + 2][ar] = av.z; sA[ak + 3][ar] = av.w;

    float4 w0 = *(const float4*)(W + (size_t)(k0 + wk) * HDIM + wc);
    float4 w1 = *(const float4*)(W + (size_t)(k0 + wk) * HDIM + wc + 4);
    *(float4*)&sW[wk][wc] = w0;
    *(float4*)&sW[wk][wc + 4] = w1;
    __syncthreads();

#pragma unroll
    for (int k = 0; k < KB; ++k) {
      float4 a = *(const float4*)&sA[k][ty * 4];
      float4 wA = *(const float4*)&sW[k][tx * 8];
      float4 wB = *(const float4*)&sW[k][tx * 8 + 4];
      float av4[4] = {a.x, a.y, a.z, a.w};
      float wv[8] = {wA.x, wA.y, wA.z, wA.w, wB.x, wB.y, wB.z, wB.w};
#pragma unroll
      for (int i = 0; i < 4; ++i)
#pragma unroll
        for (int j = 0; j < 8; ++j) acc[i][j] += av4[i] * wv[j];
    }
    __syncthreads();
  }

  float bj[8];
#pragma unroll
  for (int j = 0; j < 8; ++j) bj[j] = bias ? bias[tx * 8 + j] : 0.f;
#pragma unroll
  for (int i = 0; i < 4; ++i) {
    int grow = block_row + ty * 4 + i;
    if (grow < n) {
      float o[8];
#pragma unroll
      for (int j = 0; j < 8; ++j) o[j] = acc[i][j] + bj[j];
      *(float4*)(out + (size_t)grow * HDIM + tx * 8) = *(float4*)&o[0];
      *(float4*)(out + (size_t)grow * HDIM + tx * 8 + 4) = *(float4*)&o[4];
    }
  }
}

// ---------------------------------------------------------------------------
// CSR build: histogram of dst, then 3-kernel hierarchical exclusive scan.
// ---------------------------------------------------------------------------
__global__ __launch_bounds__(256) void hist_dst(const int* __restrict__ ei,
                                                int E, int n,
                                                int* __restrict__ deg) {
  int e = blockIdx.x * 256 + threadIdx.x;
  if (e < E) {
    int s = ei[e];
    int d = ei[E + e];
    // count only edges fill_csr will actually place, so deg == slots filled
    if ((unsigned)s < (unsigned)n && (unsigned)d < (unsigned)n)
      atomicAdd(&deg[d], 1);
  }
}

// phase 1: per-block (1024-elem chunk) sums
__global__ __launch_bounds__(1024) void scan1(const int* __restrict__ deg,
                                              int* __restrict__ partials, int n) {
  __shared__ int sm[1024];
  int i = blockIdx.x * 1024 + threadIdx.x;
  sm[threadIdx.x] = (i < n) ? deg[i] : 0;
  __syncthreads();
  for (int d = 512; d > 0; d >>= 1) {
    if (threadIdx.x < d) sm[threadIdx.x] += sm[threadIdx.x + d];
    __syncthreads();
  }
  if (threadIdx.x == 0) partials[blockIdx.x] = sm[0];
}

// phase 2: exclusive-scan the (<=1024) block partials in one block
__global__ __launch_bounds__(1024) void scan2(int* __restrict__ partials, int G) {
  __shared__ int sm[1024];
  int tid = threadIdx.x;
  int v = (tid < G) ? partials[tid] : 0;
  sm[tid] = v;
  __syncthreads();
  for (int d = 1; d < 1024; d <<= 1) {
    int t = (tid >= d) ? sm[tid - d] : 0;
    __syncthreads();
    sm[tid] += t;
    __syncthreads();
  }
  if (tid < G) partials[tid] = sm[tid] - v;  // inclusive -> exclusive
}

// phase 3: block-local exclusive scan + block offset -> off/cur
__global__ __launch_bounds__(1024) void scan3(const int* __restrict__ deg,
                                              const int* __restrict__ partials,
                                              int* __restrict__ off,
                                              int* __restrict__ cur, int n) {
  __shared__ int sm[1024];
  int tid = threadIdx.x;
  int i = blockIdx.x * 1024 + tid;
  int v = (i < n) ? deg[i] : 0;
  sm[tid] = v;
  __syncthreads();
  for (int d = 1; d < 1024; d <<= 1) {
    int t = (tid >= d) ? sm[tid - d] : 0;
    __syncthreads();
    sm[tid] += t;
    __syncthreads();
  }
  if (i < n) {
    int ex = partials[blockIdx.x] + sm[tid] - v;
    off[i] = ex;
    cur[i] = ex;
    if (i == n - 1) off[n] = ex + v;
  }
}

__global__ __launch_bounds__(256) void fill_csr(const int* __restrict__ ei,
                                                int E, int n,
                                                int* __restrict__ cur,
                                                int* __restrict__ csr) {
  int e = blockIdx.x * 256 + threadIdx.x;
  if (e < E) {
    int s = ei[e];
    int d = ei[E + e];
    if ((unsigned)d < (unsigned)n && (unsigned)s < (unsigned)n) {
      int slot = atomicAdd(&cur[d], 1);
      csr[slot] = s;
    }
  }
}

// ---------------------------------------------------------------------------
// agg_tanh: out[v] = tanh( bias + M[v] (self loop) + sum_{s in N(v)} M[s] ).
// One wave per node; lane owns float2 at feature lane*2.
// ---------------------------------------------------------------------------
__global__ __launch_bounds__(256) void agg_tanh(const float* __restrict__ M,
                                                const int* __restrict__ off,
                                                const int* __restrict__ csr,
                                                const float* __restrict__ bias,
                                                float* __restrict__ out, int n) {
  int node = (blockIdx.x * 256 + threadIdx.x) >> 6;
  int lane = threadIdx.x & 63;
  if (node >= n) return;
  int f = lane * 2;
  float2 acc = *(const float2*)(M + (size_t)node * HDIM + f);  // self loop
  acc.x += bias[f];
  acc.y += bias[f + 1];
  int s = off[node], e = off[node + 1];
  for (int base = s; base < e; base += 64) {
    int idx = base + lane;
    int msrc = (idx < e) ? csr[idx] : 0;
    int cnt = min(64, e - base);
    for (int j = 0; j < cnt; ++j) {
      int src = __shfl(msrc, j);
      float2 v = *(const float2*)(M + (size_t)src * HDIM + f);
      acc.x += v.x;
      acc.y += v.y;
    }
  }
  acc.x = tanhf(acc.x);
  acc.y = tanhf(acc.y);
  *(float2*)(out + (size_t)node * HDIM + f) = acc;
}

// ---------------------------------------------------------------------------
// agg2_head: layer-2 aggregation fused with the head.
// ---------------------------------------------------------------------------
__global__ __launch_bounds__(256) void agg2_head(
    const float* __restrict__ M, const int* __restrict__ off,
    const int* __restrict__ csr, const float* __restrict__ b2,
    const float* __restrict__ cp_w, const float* __restrict__ cp_b,
    const float* __restrict__ cls_w, const float* __restrict__ cls_b,
    float* __restrict__ out, int n) {
  int node = (blockIdx.x * 256 + threadIdx.x) >> 6;
  int lane = threadIdx.x & 63;
  if (node >= n) return;
  int f = lane * 2;
  float2 acc = *(const float2*)(M + (size_t)node * HDIM + f);
  acc.x += b2[f];
  acc.y += b2[f + 1];
  int s = off[node], e = off[node + 1];
  for (int base = s; base < e; base += 64) {
    int idx = base + lane;
    int msrc = (idx < e) ? csr[idx] : 0;
    int cnt = min(64, e - base);
    for (int j = 0; j < cnt; ++j) {
      int src = __shfl(msrc, j);
      float2 v = *(const float2*)(M + (size_t)src * HDIM + f);
      acc.x += v.x;
      acc.y += v.y;
    }
  }
  float h0 = tanhf(acc.x);
  float h1 = tanhf(acc.y);
  float4 w = *(const float4*)(cp_w + lane * 4);
  float s0 = h0 * w.x + h1 * w.z;
  float s1 = h0 * w.y + h1 * w.w;
#pragma unroll
  for (int offs = 32; offs; offs >>= 1) {
    s0 += __shfl_xor(s0, offs);
    s1 += __shfl_xor(s1, offs);
  }
  if (lane == 0) {
    float p0 = tanhf(s0 + cp_b[0]);
    float p1 = tanhf(s1 + cp_b[1]);
    float4 o;
    o.x = p0 * cls_w[0] + p1 * cls_w[4] + cls_b[0];
    o.y = p0 * cls_w[1] + p1 * cls_w[5] + cls_b[1];
    o.z = p0 * cls_w[2] + p1 * cls_w[6] + cls_b[2];
    o.w = p0 * cls_w[3] + p1 * cls_w[7] + cls_b[3];
    *(float4*)(out + (size_t)node * 4) = o;
    float* hout = out + (size_t)n * 4;
    *(float2*)(hout + (size_t)node * 2) = make_float2(p0, p1);
  }
}

extern "C" void kernel_launch(void* const* d_in, const int* in_sizes, int n_in,
                              void* d_out, int out_size, void* d_ws, size_t ws_size,
                              hipStream_t stream) {
  const float* x     = (const float*)d_in[0];
  const int*   ei    = (const int*)d_in[1];
  const float* fw    = (const float*)d_in[2];
  const float* fb    = (const float*)d_in[3];
  const float* w1    = (const float*)d_in[4];
  const float* b1    = (const float*)d_in[5];
  const float* w2    = (const float*)d_in[6];
  const float* b2    = (const float*)d_in[7];
  const float* cp_w  = (const float*)d_in[8];
  const float* cp_b  = (const float*)d_in[9];
  const float* cls_w = (const float*)d_in[10];
  const float* cls_b = (const float*)d_in[11];
  float* out = (float*)d_out;

  int n = in_sizes[0] / HDIM;
  int E = in_sizes[1] / 2;
  size_t nh = (size_t)n * HDIM;

  float* A = (float*)d_ws;        // H0 -> h1
  float* B = A + nh;              // messages M
  int* deg = (int*)(B + nh);
  int* off = deg + n;             // n+1 entries
  int* cur = off + n + 1;
  int* csr = cur + n;             // E entries
  int* partials = csr + E;        // up to 1024 entries

  int gemmBlocks = (n + BM - 1) / BM;
  int edgeBlocks = (E + 255) / 256;
  int aggBlocks = (n + 3) / 4;
  int G = (n + 1023) / 1024;      // scan chunks

  // CSR build (used by both layers)
  hipMemsetAsync(deg, 0, (size_t)n * sizeof(int), stream);
  hist_dst<<<edgeBlocks, 256, 0, stream>>>(ei, E, n, deg);
  scan1<<<G, 1024, 0, stream>>>(deg, partials, n);
  scan2<<<1, 1024, 0, stream>>>(partials, G);
  scan3<<<G, 1024, 0, stream>>>(deg, partials, off, cur, n);
  fill_csr<<<edgeBlocks, 256, 0, stream>>>(ei, E, n, cur, csr);

  // layer 0: A = x @ fw + fb
  gemm_tiled<<<gemmBlocks, 256, 0, stream>>>(x, fw, fb, A, n);
  // layer 1: B = A @ w1 ; A = tanh(b1 + agg(B))
  gemm_tiled<<<gemmBlocks, 256, 0, stream>>>(A, w1, nullptr, B, n);
  agg_tanh<<<aggBlocks, 256, 0, stream>>>(B, off, csr, b1, A, n);
  // layer 2: B = A @ w2 ; fused agg + head
  gemm_tiled<<<gemmBlocks, 256, 0, stream>>>(A, w2, nullptr, B, n);
  agg2_head<<<aggBlocks, 256, 0, stream>>>(B, off, csr, b2, cp_w, cp_b,
                                           cls_w, cls_b, out, n);
}